// Round 1
// baseline (676.535 us; speedup 1.0000x reference)
//
#include <hip/hip_runtime.h>

typedef float v4f __attribute__((ext_vector_type(4)));

#define DIM 1024
#define ROWS 8
#define PADDING_IDX 0

// log2(1e-4) in double-single form (compile-time folded)
constexpr double LD_   = -13.287712379549449;
constexpr float  L_HI  = (float)LD_;
constexpr float  L_LO  = (float)(LD_ - (double)L_HI);
constexpr float  INV2PI = 0.15915494309189535f;
// 2*pi = PI2_HI + PI2_MID; PI2_HI = 402 * 2^-6 is exact with k*PI2_HI exact for k < 2^15
constexpr float  PI2_HI  = 6.28125f;
constexpr float  PI2_MID = (float)(6.283185307179586476925287 - 6.28125);
constexpr float  LN2     = 0.69314718055994531f;

// w = (1e-4)^e = exp2(e * log2(1e-4)), accurate to ~1 ulp via double-single exponent
__device__ __forceinline__ float make_w(float e) {
    float th = e * L_HI;
    float tl = __builtin_fmaf(e, L_HI, -th) + e * L_LO;  // residual of the product + low part
    float w0 = __builtin_amdgcn_exp2f(th);
    return __builtin_fmaf(w0 * LN2, tl, w0);             // w0 * (1 + ln2*tl)
}

// reduce pos*w to revolutions in [-0.505, 0.505] with Cody-Waite (error ~3e-6 rad)
__device__ __forceinline__ float red_rev(float p, float w) {
    float ang = p * w;                                   // matches ref's fl(pos*w)
    float kf  = __builtin_rintf(ang * INV2PI);           // kf <= 20861 < 2^15
    float r   = __builtin_fmaf(kf, -PI2_HI, ang);        // exact
    r         = __builtin_fmaf(kf, -PI2_MID, r);         // single rounding
    return r * INV2PI;
}

__global__ __launch_bounds__(256) void pe_kernel(const int* __restrict__ x,
                                                 const float* __restrict__ W,
                                                 float* __restrict__ out,
                                                 int N) {
    const int tid  = threadIdx.x;
    const int j0   = tid << 2;                 // 4 columns per thread
    const int row0 = blockIdx.x * ROWS;

    // Column frequencies: j0 (even, cos) -> e=j0/D; j0+1 (sin) & j0+2 (cos) -> e=(j0+2)/D;
    // j0+3 (sin) -> e=(j0+4)/D. All exact in fp32.
    const float wA = make_w((float)j0        * (1.0f / 1024.0f));
    const float wB = make_w((float)(j0 + 2)  * (1.0f / 1024.0f));
    const float wC = make_w((float)(j0 + 4)  * (1.0f / 1024.0f));

#pragma unroll
    for (int r = 0; r < ROWS; ++r) {
        const int row = row0 + r;
        if (row >= N) break;
        const int   idx = x[row];              // block-uniform -> s_load + scalar branch
        const float p   = (float)(row + 1);    // 1-based position, exact (<= 2^17)

        v4f emb = {0.f, 0.f, 0.f, 0.f};
        if (idx != PADDING_IDX) {
            emb = *(const v4f*)(W + (size_t)idx * DIM + j0);
        }

        const float revB = red_rev(p, wB);     // shared by the sin/cos pair
        v4f o;
        o.x = emb.x + __builtin_amdgcn_cosf(red_rev(p, wA));
        o.y = emb.y + __builtin_amdgcn_sinf(revB);
        o.z = emb.z + __builtin_amdgcn_cosf(revB);
        o.w = emb.w + __builtin_amdgcn_sinf(red_rev(p, wC));

        // output is write-once: stream past L2/L3 so W stays cache-resident
        __builtin_nontemporal_store(o, (v4f*)(out + (size_t)row * DIM + j0));
    }
}

extern "C" void kernel_launch(void* const* d_in, const int* in_sizes, int n_in,
                              void* d_out, int out_size, void* d_ws, size_t ws_size,
                              hipStream_t stream) {
    const int*   x   = (const int*)d_in[0];
    const float* W   = (const float*)d_in[1];
    float*       out = (float*)d_out;
    const int    N   = in_sizes[0];

    const int grid = (N + ROWS - 1) / ROWS;
    hipLaunchKernelGGL(pe_kernel, dim3(grid), dim3(256), 0, stream, x, W, out, N);
}